// Round 1
// baseline (603.204 us; speedup 1.0000x reference)
//
#include <hip/hip_runtime.h>
#include <math.h>

// ---------------------------------------------------------------------------
// VectorQuantize fused kernel for MI355X (gfx950).
// Shapes: z[16][1024][4096] f32, cb[1024][8], proj dims 1024<->8.
// Outputs concat (floats): z_out (16*1024*4096) | commit[16] | cb_loss[16] |
//                          indices[16*4096] (as float) | z_e (16*8*4096)
// ---------------------------------------------------------------------------

namespace {
constexpr int kB  = 16;
constexpr int kD  = 1024;   // D_IN
constexpr int kT  = 4096;
constexpr int kCB = 1024;   // codebook size
constexpr int kC  = 8;      // codebook dim
constexpr float kEps = 1e-12f;

constexpr size_t N_ZOUT    = (size_t)kB * kD * kT;         // 67108864
constexpr size_t OFF_COMMIT = N_ZOUT;                      // +16
constexpr size_t OFF_CBL    = OFF_COMMIT + kB;             // +16
constexpr size_t OFF_IDX    = OFF_CBL + kB;                // +65536
constexpr size_t OFF_ZE     = OFF_IDX + (size_t)kB * kT;   // +524288
}

// Prep: weight-norm weights (transposed) + normalized codebook into ws.
// blocks 0-7:  w_in_t[d][o] = in_g[o] * in_v[o][d] / ||in_v[o,:]||   (norm over 1024)
// blocks 8-11: cb_n_t[k][c] = cb[k][c] / max(||cb[k,:]||, EPS)
// blocks 12-15: w_out_t[o][c] = out_g[o] * out_v[o][c] / ||out_v[o,:]|| (norm over 8)
__global__ void vq_prep(const float* __restrict__ in_v, const float* __restrict__ in_g,
                        const float* __restrict__ out_v, const float* __restrict__ out_g,
                        const float* __restrict__ cb,
                        float* __restrict__ w_in_t, float* __restrict__ w_out_t,
                        float* __restrict__ cb_n_t)
{
    __shared__ float red[4];
    const int blk = blockIdx.x;
    const int tid = threadIdx.x;
    if (blk < 8) {
        const int o = blk;
        float ss = 0.f;
        for (int d = tid; d < kD; d += 256) {
            float v = in_v[o * kD + d];
            ss = fmaf(v, v, ss);
        }
        #pragma unroll
        for (int off = 32; off; off >>= 1) ss += __shfl_xor(ss, off);
        if ((tid & 63) == 0) red[tid >> 6] = ss;
        __syncthreads();
        const float scale = in_g[o] / sqrtf(red[0] + red[1] + red[2] + red[3]);
        for (int d = tid; d < kD; d += 256)
            w_in_t[d * kC + o] = scale * in_v[o * kD + d];
    } else if (blk < 12) {
        const int r = (blk - 8) * 256 + tid;
        float4 a = reinterpret_cast<const float4*>(cb)[2 * r];
        float4 b = reinterpret_cast<const float4*>(cb)[2 * r + 1];
        float n = sqrtf(a.x*a.x + a.y*a.y + a.z*a.z + a.w*a.w +
                        b.x*b.x + b.y*b.y + b.z*b.z + b.w*b.w);
        float s = 1.f / fmaxf(n, kEps);
        a.x *= s; a.y *= s; a.z *= s; a.w *= s;
        b.x *= s; b.y *= s; b.z *= s; b.w *= s;
        reinterpret_cast<float4*>(cb_n_t)[2 * r]     = a;
        reinterpret_cast<float4*>(cb_n_t)[2 * r + 1] = b;
    } else {
        const int r = (blk - 12) * 256 + tid;
        float4 a = reinterpret_cast<const float4*>(out_v)[2 * r];
        float4 b = reinterpret_cast<const float4*>(out_v)[2 * r + 1];
        float n = sqrtf(a.x*a.x + a.y*a.y + a.z*a.z + a.w*a.w +
                        b.x*b.x + b.y*b.y + b.z*b.z + b.w*b.w);
        float s = out_g[r] / n;   // reference uses no eps here
        a.x *= s; a.y *= s; a.z *= s; a.w *= s;
        b.x *= s; b.y *= s; b.z *= s; b.w *= s;
        reinterpret_cast<float4*>(w_out_t)[2 * r]     = a;
        reinterpret_cast<float4*>(w_out_t)[2 * r + 1] = b;
    }
}

// Main fused kernel: one block = 64 tokens (one batch each, since 4096 % 64 == 0).
// 256 threads = 4 waves. tx = token lane (0..63), ty = wave (0..3).
__global__ __launch_bounds__(256, 4)
void vq_main(const float* __restrict__ z,
             const float* __restrict__ in_b, const float* __restrict__ out_b,
             const float* __restrict__ cb,
             const float* __restrict__ w_in_t, const float* __restrict__ w_out_t,
             const float* __restrict__ cb_n_t,
             float* __restrict__ out)
{
    __shared__ float s_acc[4][kC][64];  // 8 KB: partial z_e per ty
    __shared__ float s_ze[kC][64];      // 2 KB
    __shared__ float s_zq[kC][64];      // 2 KB
    __shared__ float s_sim[4][64];
    __shared__ int   s_idx[4][64];

    const int tid = threadIdx.x;
    const int tx = tid & 63;
    const int ty = tid >> 6;
    const int g0 = blockIdx.x * 64;     // global token base
    const int b  = g0 >> 12;            // / kT
    const int t0 = g0 & (kT - 1);

    // ---------------- Phase A: in-projection (z_e = w_in @ z + in_b) --------
    // wave ty covers d in [ty*256, ty*256+256); lane tx is token t0+tx.
    const float* zp = z + ((size_t)b * kD + (size_t)ty * 256) * kT + t0 + tx;
    const float4* wq = reinterpret_cast<const float4*>(w_in_t + (size_t)ty * 256 * kC);
    float acc[kC];
    #pragma unroll
    for (int c = 0; c < kC; c++) acc[c] = 0.f;

    #pragma unroll 4
    for (int i = 0; i < 256; i++) {
        float zv = zp[(size_t)i * kT];          // coalesced 256B / wave
        float4 w0 = wq[2 * i];                  // wave-uniform broadcast
        float4 w1 = wq[2 * i + 1];
        acc[0] = fmaf(zv, w0.x, acc[0]);
        acc[1] = fmaf(zv, w0.y, acc[1]);
        acc[2] = fmaf(zv, w0.z, acc[2]);
        acc[3] = fmaf(zv, w0.w, acc[3]);
        acc[4] = fmaf(zv, w1.x, acc[4]);
        acc[5] = fmaf(zv, w1.y, acc[5]);
        acc[6] = fmaf(zv, w1.z, acc[6]);
        acc[7] = fmaf(zv, w1.w, acc[7]);
    }
    #pragma unroll
    for (int c = 0; c < kC; c++) s_acc[ty][c][tx] = acc[c];
    __syncthreads();

    // reduce 4 partials; thread (tx,ty) handles channels 2ty, 2ty+1
    #pragma unroll
    for (int cc = 0; cc < 2; cc++) {
        const int c = ty * 2 + cc;
        float v = s_acc[0][c][tx] + s_acc[1][c][tx] + s_acc[2][c][tx] + s_acc[3][c][tx]
                + in_b[c];
        s_ze[c][tx] = v;
    }
    __syncthreads();

    // ---------------- VQ: argmax of z_e . cb_n over codes --------------------
    // (== argmin of reference cosine distance; per-token terms constant)
    float ze[kC];
    #pragma unroll
    for (int c = 0; c < kC; c++) ze[c] = s_ze[c][tx];

    float best = -INFINITY;
    int bk = 0;
    const float4* cq = reinterpret_cast<const float4*>(cb_n_t + (size_t)ty * 256 * kC);
    #pragma unroll 2
    for (int j = 0; j < 256; j++) {
        float4 c0 = cq[2 * j];                  // wave-uniform broadcast
        float4 c1 = cq[2 * j + 1];
        float sim = ze[0] * c0.x;
        sim = fmaf(ze[1], c0.y, sim);
        sim = fmaf(ze[2], c0.z, sim);
        sim = fmaf(ze[3], c0.w, sim);
        sim = fmaf(ze[4], c1.x, sim);
        sim = fmaf(ze[5], c1.y, sim);
        sim = fmaf(ze[6], c1.z, sim);
        sim = fmaf(ze[7], c1.w, sim);
        if (sim > best) { best = sim; bk = ty * 256 + j; }   // strict > keeps first
    }
    s_sim[ty][tx] = best;
    s_idx[ty][tx] = bk;
    __syncthreads();

    // leader wave (ty==0): finalize per-token results
    if (ty == 0) {
        float bs = s_sim[0][tx];
        int   bi = s_idx[0][tx];
        #pragma unroll
        for (int g = 1; g < 4; g++) {
            float v = s_sim[g][tx];
            if (v > bs) { bs = v; bi = s_idx[g][tx]; }   // strict >: lower k wins ties
        }
        out[OFF_IDX + (size_t)b * kT + t0 + tx] = (float)bi;

        float4 q0 = reinterpret_cast<const float4*>(cb)[2 * bi];
        float4 q1 = reinterpret_cast<const float4*>(cb)[2 * bi + 1];
        float zq[kC] = {q0.x, q0.y, q0.z, q0.w, q1.x, q1.y, q1.z, q1.w};

        float lsum = 0.f;
        #pragma unroll
        for (int c = 0; c < kC; c++) {
            s_zq[c][tx] = zq[c];
            float d = ze[c] - zq[c];
            lsum = fmaf(d, d, lsum);
            out[OFF_ZE + (size_t)b * (kC * kT) + (size_t)c * kT + t0 + tx] = ze[c];
        }
        // wave-reduce loss over the 64 tokens
        #pragma unroll
        for (int off = 32; off; off >>= 1) lsum += __shfl_xor(lsum, off);
        if (tx == 0) {
            const float lv = lsum * (1.f / (kC * kT));   // mean over (8, 4096)
            atomicAdd(&out[OFF_COMMIT + b], lv);
            atomicAdd(&out[OFF_CBL + b], lv);            // identical forward value
        }
    }
    __syncthreads();

    // ---------------- Phase B: out-projection (z_out = w_out @ z_q + out_b) --
    // wave ty covers o in [ty*256, ty*256+256); lane tx is token t0+tx.
    float zq[kC];
    #pragma unroll
    for (int c = 0; c < kC; c++) zq[c] = s_zq[c][tx];

    const int o0 = ty * 256;
    const float4* wo = reinterpret_cast<const float4*>(w_out_t + (size_t)o0 * kC);
    float* outp = out + ((size_t)b * kD + o0) * kT + t0 + tx;
    #pragma unroll 4
    for (int j = 0; j < 256; j++) {
        float4 w0 = wo[2 * j];                  // wave-uniform broadcast
        float4 w1 = wo[2 * j + 1];
        float r = out_b[o0 + j];
        r = fmaf(zq[0], w0.x, r);
        r = fmaf(zq[1], w0.y, r);
        r = fmaf(zq[2], w0.z, r);
        r = fmaf(zq[3], w0.w, r);
        r = fmaf(zq[4], w1.x, r);
        r = fmaf(zq[5], w1.y, r);
        r = fmaf(zq[6], w1.z, r);
        r = fmaf(zq[7], w1.w, r);
        outp[(size_t)j * kT] = r;               // coalesced 256B / wave
    }
}

extern "C" void kernel_launch(void* const* d_in, const int* in_sizes, int n_in,
                              void* d_out, int out_size, void* d_ws, size_t ws_size,
                              hipStream_t stream) {
    const float* z     = (const float*)d_in[0];
    const float* in_v  = (const float*)d_in[1];
    const float* in_g  = (const float*)d_in[2];
    const float* in_b  = (const float*)d_in[3];
    const float* out_v = (const float*)d_in[4];
    const float* out_g = (const float*)d_in[5];
    const float* out_b = (const float*)d_in[6];
    const float* cb    = (const float*)d_in[7];
    float* out = (float*)d_out;

    float* w_in_t  = (float*)d_ws;               // [1024][8]
    float* w_out_t = w_in_t + (size_t)kD * kC;   // [1024][8]
    float* cb_n_t  = w_out_t + (size_t)kD * kC;  // [1024][8]

    vq_prep<<<16, 256, 0, stream>>>(in_v, in_g, out_v, out_g, cb,
                                    w_in_t, w_out_t, cb_n_t);
    // zero the loss accumulators (d_out is poisoned 0xAA before every launch)
    hipMemsetAsync(out + OFF_COMMIT, 0, 2 * kB * sizeof(float), stream);
    vq_main<<<(kB * kT) / 64, 256, 0, stream>>>(z, in_b, out_b, cb,
                                                w_in_t, w_out_t, cb_n_t, out);
}

// Round 3
// 522.914 us; speedup vs baseline: 1.1535x; 1.1535x over previous
//
#include <hip/hip_runtime.h>
#include <math.h>

// ---------------------------------------------------------------------------
// VectorQuantize fused kernel for MI355X (gfx950) — R2: float4 everywhere,
// no macros (R1 died on macro-parameter/member-name collision: zv.w).
// Shapes: z[16][1024][4096] f32, cb[1024][8], proj dims 1024<->8.
// Outputs concat (floats): z_out (16*1024*4096) | commit[16] | cb_loss[16] |
//                          indices[16*4096] (as float) | z_e (16*8*4096)
// ---------------------------------------------------------------------------

namespace {
constexpr int kB  = 16;
constexpr int kD  = 1024;   // D_IN
constexpr int kT  = 4096;
constexpr int kCB = 1024;   // codebook size
constexpr int kC  = 8;      // codebook dim
constexpr float kEps = 1e-12f;

constexpr size_t N_ZOUT    = (size_t)kB * kD * kT;         // 67108864
constexpr size_t OFF_COMMIT = N_ZOUT;                      // +16
constexpr size_t OFF_CBL    = OFF_COMMIT + kB;             // +16
constexpr size_t OFF_IDX    = OFF_CBL + kB;                // +65536
constexpr size_t OFF_ZE     = OFF_IDX + (size_t)kB * kT;   // +524288
}

// Prep: weight-norm weights (transposed) + normalized codebook into ws.
__global__ void vq_prep(const float* __restrict__ in_v, const float* __restrict__ in_g,
                        const float* __restrict__ out_v, const float* __restrict__ out_g,
                        const float* __restrict__ cb,
                        float* __restrict__ w_in_t, float* __restrict__ w_out_t,
                        float* __restrict__ cb_n_t)
{
    __shared__ float red[4];
    const int blk = blockIdx.x;
    const int tid = threadIdx.x;
    if (blk < 8) {
        const int o = blk;
        float ss = 0.f;
        for (int d = tid; d < kD; d += 256) {
            float v = in_v[o * kD + d];
            ss = fmaf(v, v, ss);
        }
        #pragma unroll
        for (int off = 32; off; off >>= 1) ss += __shfl_xor(ss, off);
        if ((tid & 63) == 0) red[tid >> 6] = ss;
        __syncthreads();
        const float scale = in_g[o] / sqrtf(red[0] + red[1] + red[2] + red[3]);
        for (int d = tid; d < kD; d += 256)
            w_in_t[d * kC + o] = scale * in_v[o * kD + d];
    } else if (blk < 12) {
        const int r = (blk - 8) * 256 + tid;
        float4 a = reinterpret_cast<const float4*>(cb)[2 * r];
        float4 b = reinterpret_cast<const float4*>(cb)[2 * r + 1];
        float n = sqrtf(a.x*a.x + a.y*a.y + a.z*a.z + a.w*a.w +
                        b.x*b.x + b.y*b.y + b.z*b.z + b.w*b.w);
        float s = 1.f / fmaxf(n, kEps);
        a.x *= s; a.y *= s; a.z *= s; a.w *= s;
        b.x *= s; b.y *= s; b.z *= s; b.w *= s;
        reinterpret_cast<float4*>(cb_n_t)[2 * r]     = a;
        reinterpret_cast<float4*>(cb_n_t)[2 * r + 1] = b;
    } else {
        const int r = (blk - 12) * 256 + tid;
        float4 a = reinterpret_cast<const float4*>(out_v)[2 * r];
        float4 b = reinterpret_cast<const float4*>(out_v)[2 * r + 1];
        float n = sqrtf(a.x*a.x + a.y*a.y + a.z*a.z + a.w*a.w +
                        b.x*b.x + b.y*b.y + b.z*b.z + b.w*b.w);
        float s = out_g[r] / n;   // reference uses no eps here
        a.x *= s; a.y *= s; a.z *= s; a.w *= s;
        b.x *= s; b.y *= s; b.z *= s; b.w *= s;
        reinterpret_cast<float4*>(w_out_t)[2 * r]     = a;
        reinterpret_cast<float4*>(w_out_t)[2 * r + 1] = b;
    }
}

// Main fused kernel: block = 64 tokens, 256 threads = 4 waves.
// Thread roles: tg = tid&15 (owns 4 tokens 4tg..4tg+3 via float4),
//               sl = tid>>4 (slice 0..15: 64 d-rows / 64 codes / 64 o-rows).
__global__ __launch_bounds__(256, 4)
void vq_main(const float* __restrict__ z,
             const float* __restrict__ in_b, const float* __restrict__ out_b,
             const float* __restrict__ cb,
             const float* __restrict__ w_in_t, const float* __restrict__ w_out_t,
             const float* __restrict__ cb_n_t,
             float* __restrict__ out)
{
    __shared__ float s_red[4][kC][64];   // 8 KB: per-wave partial z_e
    __shared__ float s_ze[kC][64];       // 2 KB
    __shared__ float s_zq[kC][64];       // 2 KB
    __shared__ float s_sim[16][64];      // 4 KB
    __shared__ int   s_idx[16][64];      // 4 KB

    const int tid = threadIdx.x;
    const int tg = tid & 15;            // token group (4 tokens)
    const int sl = tid >> 4;            // slice 0..15
    const int wv = tid >> 6;            // wave 0..3
    const int g0 = blockIdx.x * 64;     // global token base
    const int b  = g0 >> 12;            // / kT
    const int t0 = g0 & (kT - 1);

    // ---------------- Phase A: z_e = w_in @ z + in_b ------------------------
    // slice sl covers d in [sl*64, sl*64+64); float4 = 4 tokens per load.
    const float* zp = z + ((size_t)b * kD + (size_t)sl * 64) * kT + t0 + 4 * tg;
    const float4* wq = reinterpret_cast<const float4*>(w_in_t) + (size_t)sl * 128;
    float acc[kC][4];
    #pragma unroll
    for (int c = 0; c < kC; c++)
        #pragma unroll
        for (int j = 0; j < 4; j++) acc[c][j] = 0.f;

    #pragma unroll 4
    for (int i = 0; i < 64; i++) {
        const float4 zv = *reinterpret_cast<const float4*>(zp + (size_t)i * kT); // 1KB/wave
        const float4 w0 = wq[2 * i];        // uniform within 16-lane group
        const float4 w1 = wq[2 * i + 1];
        const float zl[4] = {zv.x, zv.y, zv.z, zv.w};
        const float wl[kC] = {w0.x, w0.y, w0.z, w0.w, w1.x, w1.y, w1.z, w1.w};
        #pragma unroll
        for (int c = 0; c < kC; c++)
            #pragma unroll
            for (int j = 0; j < 4; j++)
                acc[c][j] = fmaf(zl[j], wl[c], acc[c][j]);
    }
    // reduce the wave's 4 slices in-register (lane>>4 spans them)
    #pragma unroll
    for (int c = 0; c < kC; c++)
        #pragma unroll
        for (int j = 0; j < 4; j++) {
            float v = acc[c][j];
            v += __shfl_xor(v, 16);
            v += __shfl_xor(v, 32);
            acc[c][j] = v;
        }
    if ((tid & 48) == 0) {               // lanes 0-15 of each wave
        #pragma unroll
        for (int c = 0; c < kC; c++)
            #pragma unroll
            for (int j = 0; j < 4; j++) s_red[wv][c][4 * tg + j] = acc[c][j];
    }
    __syncthreads();

    // final cross-wave reduce: 512 outputs / 256 threads = 2 each
    {
        const int c  = tid >> 5;         // 0..7
        const int t2 = (tid & 31) * 2;
        #pragma unroll
        for (int k = 0; k < 2; k++) {
            const int t = t2 + k;
            s_ze[c][t] = s_red[0][c][t] + s_red[1][c][t] + s_red[2][c][t]
                       + s_red[3][c][t] + in_b[c];
        }
    }
    __syncthreads();

    // ---------------- VQ: argmax of z_e . cb_n over codes -------------------
    // (== argmin of reference cosine distance; per-token terms constant)
    // slice sl covers codes [sl*64, sl*64+64); 4 tokens per thread.
    float zef[4][kC];
    #pragma unroll
    for (int j = 0; j < 4; j++)
        #pragma unroll
        for (int c = 0; c < kC; c++) zef[j][c] = s_ze[c][4 * tg + j];

    float best[4] = {-INFINITY, -INFINITY, -INFINITY, -INFINITY};
    int   bk[4]   = {sl * 64, sl * 64, sl * 64, sl * 64};
    const float4* cq = reinterpret_cast<const float4*>(cb_n_t) + (size_t)sl * 128;
    #pragma unroll 2
    for (int i = 0; i < 64; i++) {
        const float4 c0 = cq[2 * i];
        const float4 c1 = cq[2 * i + 1];
        const float cl[kC] = {c0.x, c0.y, c0.z, c0.w, c1.x, c1.y, c1.z, c1.w};
        #pragma unroll
        for (int j = 0; j < 4; j++) {
            float sim = zef[j][0] * cl[0];
            #pragma unroll
            for (int c = 1; c < kC; c++) sim = fmaf(zef[j][c], cl[c], sim);
            if (sim > best[j]) { best[j] = sim; bk[j] = sl * 64 + i; } // first max
        }
    }
    #pragma unroll
    for (int j = 0; j < 4; j++) {
        s_sim[sl][4 * tg + j] = best[j];
        s_idx[sl][4 * tg + j] = bk[j];
    }
    __syncthreads();

    // per-token finalize: wave 0 (tid<64), one token each
    if (tid < 64) {
        const int t = tid;
        float bs = s_sim[0][t];
        int   bi = s_idx[0][t];
        #pragma unroll
        for (int g = 1; g < 16; g++) {
            const float v = s_sim[g][t];
            if (v > bs) { bs = v; bi = s_idx[g][t]; }   // strict >: lower slice wins
        }
        out[OFF_IDX + (size_t)b * kT + t0 + t] = (float)bi;

        const float4 q0 = reinterpret_cast<const float4*>(cb)[2 * bi];
        const float4 q1 = reinterpret_cast<const float4*>(cb)[2 * bi + 1];
        const float zq[kC] = {q0.x, q0.y, q0.z, q0.w, q1.x, q1.y, q1.z, q1.w};

        float lsum = 0.f;
        #pragma unroll
        for (int c = 0; c < kC; c++) {
            s_zq[c][t] = zq[c];
            const float ze = s_ze[c][t];
            const float d = ze - zq[c];
            lsum = fmaf(d, d, lsum);
            out[OFF_ZE + (size_t)b * (kC * kT) + (size_t)c * kT + t0 + t] = ze;
        }
        #pragma unroll
        for (int off = 32; off; off >>= 1) lsum += __shfl_xor(lsum, off);
        if (tid == 0) {
            const float lv = lsum * (1.f / (kC * kT));
            atomicAdd(&out[OFF_COMMIT + b], lv);
            atomicAdd(&out[OFF_CBL + b], lv);            // identical forward value
        }
    }
    __syncthreads();

    // ---------------- Phase B: z_out = w_out @ z_q + out_b ------------------
    // slice sl covers o in [sl*64, sl*64+64); 4 tokens per thread (float4 store).
    float zqr[4][kC];
    #pragma unroll
    for (int j = 0; j < 4; j++)
        #pragma unroll
        for (int c = 0; c < kC; c++) zqr[j][c] = s_zq[c][4 * tg + j];

    const float4* wo = reinterpret_cast<const float4*>(w_out_t) + (size_t)sl * 128;
    const float*  bo = out_b + sl * 64;
    float* op = out + ((size_t)b * kD + (size_t)sl * 64) * kT + t0 + 4 * tg;
    #pragma unroll 4
    for (int i = 0; i < 64; i++) {
        const float4 w0 = wo[2 * i];            // uniform within 16-lane group
        const float4 w1 = wo[2 * i + 1];
        const float wl[kC] = {w0.x, w0.y, w0.z, w0.w, w1.x, w1.y, w1.z, w1.w};
        const float bias = bo[i];
        float rr[4];
        #pragma unroll
        for (int j = 0; j < 4; j++) {
            float v = bias;
            #pragma unroll
            for (int c = 0; c < kC; c++) v = fmaf(zqr[j][c], wl[c], v);
            rr[j] = v;
        }
        const float4 r = make_float4(rr[0], rr[1], rr[2], rr[3]);
        *reinterpret_cast<float4*>(op + (size_t)i * kT) = r;   // 1KB/wave
    }
}

extern "C" void kernel_launch(void* const* d_in, const int* in_sizes, int n_in,
                              void* d_out, int out_size, void* d_ws, size_t ws_size,
                              hipStream_t stream) {
    const float* z     = (const float*)d_in[0];
    const float* in_v  = (const float*)d_in[1];
    const float* in_g  = (const float*)d_in[2];
    const float* in_b  = (const float*)d_in[3];
    const float* out_v = (const float*)d_in[4];
    const float* out_g = (const float*)d_in[5];
    const float* out_b = (const float*)d_in[6];
    const float* cb    = (const float*)d_in[7];
    float* out = (float*)d_out;

    float* w_in_t  = (float*)d_ws;               // [1024][8]
    float* w_out_t = w_in_t + (size_t)kD * kC;   // [1024][8]
    float* cb_n_t  = w_out_t + (size_t)kD * kC;  // [1024][8]

    vq_prep<<<16, 256, 0, stream>>>(in_v, in_g, out_v, out_g, cb,
                                    w_in_t, w_out_t, cb_n_t);
    // zero the loss accumulators (d_out is poisoned 0xAA before every launch)
    (void)hipMemsetAsync(out + OFF_COMMIT, 0, 2 * kB * sizeof(float), stream);
    vq_main<<<(kB * kT) / 64, 256, 0, stream>>>(z, in_b, out_b, cb,
                                                w_in_t, w_out_t, cb_n_t, out);
}